// Round 6
// baseline (671.642 us; speedup 1.0000x reference)
//
#include <hip/hip_runtime.h>
#include <hip/hip_bf16.h>

// ---------------------------------------------------------------------------
// CFGSubASTExpressionCombiner: counting-sort by segment, Q proj (fp32 gather ->
// bf16 MFMA), fused K|V proj (single fp32 gather, two accumulators),
// CSR segment softmax+pool (no atomics), output GEMM.
// D = 256, H = 8, HD = 32, OUT = 256.
// NOTES:
//  - no hipMemsetAsync in the graph (in-graph small fills ~235us each, r3).
//  - scan is 3-phase multi-block (single-block scan was 233us on 1 CU, r4).
//  - no separate enc->bf16 pass (was 614MB traffic, r5); GEMMs gather fp32
//    rows directly and convert during LDS staging. K+V fused: one gather.
// ---------------------------------------------------------------------------

typedef __attribute__((ext_vector_type(8))) short bf16x8;
typedef __attribute__((ext_vector_type(4))) float f32x4;

#define DEV __device__ __forceinline__

DEV float bf2f(unsigned short u) {
    union { unsigned int i; float f; } x;
    x.i = ((unsigned int)u) << 16;
    return x.f;
}

DEV unsigned short f2bf(float f) {
    union { float f; unsigned int i; } x;
    x.f = f;
    unsigned int i = x.i;
    unsigned int r = 0x7fffu + ((i >> 16) & 1u);   // round-to-nearest-even
    return (unsigned short)((i + r) >> 16);
}

// ---------------------------------------------------------------------------
// Weight prep: transpose fp32 [K][N] weights into bf16 [N][K] layout.
// ---------------------------------------------------------------------------
__global__ void convert_weights(const float* __restrict__ Wq,
                                const float* __restrict__ Wk,
                                const float* __restrict__ Wv,
                                const float* __restrict__ Wo,
                                unsigned short* __restrict__ Wtq,
                                unsigned short* __restrict__ Wtk,
                                unsigned short* __restrict__ Wtv,
                                unsigned short* __restrict__ Wto) {
    int t = blockIdx.x * 256 + threadIdx.x;
    if (t >= 4 * 65536) return;
    int which = t >> 16;
    int u = t & 65535;
    int n = u >> 8, k = u & 255;
    const float* W = which == 0 ? Wq : which == 1 ? Wk : which == 2 ? Wv : Wo;
    unsigned short* Wt = which == 0 ? Wtq : which == 1 ? Wtk : which == 2 ? Wtv : Wto;
    Wt[u] = f2bf(W[k * 256 + n]);
}

// ---------------------------------------------------------------------------
// Counting sort of mapping entries by segment id.
// ---------------------------------------------------------------------------
__global__ void zero_kernel(int* __restrict__ p, int n) {
    int i = blockIdx.x * 256 + threadIdx.x;
    if (i < n) p[i] = 0;
}

__global__ void hist_kernel(const int* __restrict__ map_val,
                            int* __restrict__ counts, int M) {
    int m = blockIdx.x * 256 + threadIdx.x;
    if (m < M) atomicAdd(&counts[map_val[m]], 1);
}

// ---- 3-phase exclusive scan over counts[S] -> offsets[S+1], cursor[S] ----
__global__ __launch_bounds__(256) void scan_p1(const int* __restrict__ counts,
                                               int* __restrict__ bsum, int S) {
    const int i = blockIdx.x * 256 + threadIdx.x;
    int v = (i < S) ? counts[i] : 0;
#pragma unroll
    for (int d = 1; d < 64; d <<= 1) v += __shfl_xor(v, d);
    __shared__ int ws[4];
    if ((threadIdx.x & 63) == 0) ws[threadIdx.x >> 6] = v;
    __syncthreads();
    if (threadIdx.x == 0) bsum[blockIdx.x] = ws[0] + ws[1] + ws[2] + ws[3];
}

__global__ __launch_bounds__(256) void scan_p2(const int* __restrict__ bsum,
                                               int* __restrict__ bpref,
                                               int* __restrict__ offsets,
                                               int nb, int S) {
    __shared__ int part[256];
    const int t = threadIdx.x;
    const int chunk = (nb + 255) / 256;
    const int lo = t * chunk;
    const int hi = min(lo + chunk, nb);
    int sum = 0;
    for (int i = lo; i < hi; ++i) sum += bsum[i];
    part[t] = sum;
    __syncthreads();
    for (int d = 1; d < 256; d <<= 1) {
        int v = (t >= d) ? part[t - d] : 0;
        __syncthreads();
        part[t] += v;
        __syncthreads();
    }
    int run = (t > 0) ? part[t - 1] : 0;
    for (int i = lo; i < hi; ++i) {
        bpref[i] = run;
        run += bsum[i];
    }
    if (t == 255) offsets[S] = part[255];
}

__global__ __launch_bounds__(256) void scan_p3(const int* __restrict__ counts,
                                               const int* __restrict__ bpref,
                                               int* __restrict__ offsets,
                                               int* __restrict__ cursor, int S) {
    __shared__ int sh[256];
    const int t = threadIdx.x;
    const int i = blockIdx.x * 256 + t;
    const int v = (i < S) ? counts[i] : 0;
    sh[t] = v;
    __syncthreads();
    for (int d = 1; d < 256; d <<= 1) {
        int u = (t >= d) ? sh[t - d] : 0;
        __syncthreads();
        sh[t] += u;
        __syncthreads();
    }
    if (i < S) {
        const int e = sh[t] - v + bpref[blockIdx.x];
        offsets[i] = e;
        cursor[i] = e;
    }
}

__global__ void scatter_kernel(const int* __restrict__ map_key,
                               const int* __restrict__ map_val,
                               int* __restrict__ cursor,
                               int* __restrict__ sorted_src, int M) {
    int m = blockIdx.x * 256 + threadIdx.x;
    if (m >= M) return;
    int seg = map_val[m];
    int pos = atomicAdd(&cursor[seg], 1);
    sorted_src[pos] = map_key[m];
}

// ---------------------------------------------------------------------------
// GEMM: Out[dst(r)][n] = sum_k A[src(r)][k] * Wt[n][k] + bias[n]
// A: fp32 (convert on stage) or bf16. Tile 128(M) x 256(N), K=256 in 4x64.
// 512 threads = 8 waves, wave (wm,wn) in 2x4 grid owns a 64x64 quadrant.
// ---------------------------------------------------------------------------
template <bool GATHER, bool SCATTER, bool A_BF16, bool OUT_F32>
__global__ __launch_bounds__(512) void gemm256(
    const void* __restrict__ Aptr,
    const int* __restrict__ srcIdx,
    const int* __restrict__ dstIdx,
    const unsigned short* __restrict__ Wt,
    const float* __restrict__ bias,
    void* __restrict__ Out,
    int nrows, int ldo) {
    __shared__ unsigned short Alds[128][72];
    __shared__ unsigned short Blds[256][72];

    const int tm = blockIdx.x;
    const int tid = threadIdx.x;
    const int wave = tid >> 6, lane = tid & 63;
    const int wm = wave >> 2, wn = wave & 3;

    const int c8 = (tid & 7) * 8;
    const int rb = tid >> 3;    // 0..63  (bf16 A staging / B staging)
    const int c4 = (tid & 15) * 4;
    const int ra = tid >> 4;    // 0..31  (fp32 A staging)

    f32x4 acc[4][4] = {};

    // gather source rows + first k-tile prefetch
    long srcA[4];
    float4 a4[4];
    uint4 ab0, ab1;
    const unsigned short* arow0 = nullptr;
    const unsigned short* arow1 = nullptr;
    if constexpr (!A_BF16) {
#pragma unroll
        for (int p = 0; p < 4; ++p) {
            const int gr = tm * 128 + p * 32 + ra;
            srcA[p] = (gr < nrows) ? (GATHER ? (long)srcIdx[gr] : (long)gr) : 0;
        }
#pragma unroll
        for (int p = 0; p < 4; ++p)
            a4[p] = *(const float4*)((const float*)Aptr + srcA[p] * 256 + c4);
    } else {
        const int gr0 = tm * 128 + rb;
        const int gr1 = gr0 + 64;
        long s0 = (gr0 < nrows) ? (GATHER ? (long)srcIdx[gr0] : (long)gr0) : 0;
        long s1 = (gr1 < nrows) ? (GATHER ? (long)srcIdx[gr1] : (long)gr1) : 0;
        arow0 = (const unsigned short*)Aptr + s0 * 256 + c8;
        arow1 = (const unsigned short*)Aptr + s1 * 256 + c8;
        ab0 = *(const uint4*)(arow0);
        ab1 = *(const uint4*)(arow1);
    }

    for (int kt = 0; kt < 4; ++kt) {
        const int k0 = kt * 64;

        // ---- stage A ----
        if constexpr (!A_BF16) {
#pragma unroll
            for (int p = 0; p < 4; ++p) {
                unsigned int lo = (unsigned int)f2bf(a4[p].x) | ((unsigned int)f2bf(a4[p].y) << 16);
                unsigned int hi = (unsigned int)f2bf(a4[p].z) | ((unsigned int)f2bf(a4[p].w) << 16);
                *(uint2*)(&Alds[p * 32 + ra][c4]) = make_uint2(lo, hi);
            }
        } else {
            *(uint4*)(&Alds[rb][c8])      = ab0;
            *(uint4*)(&Alds[rb + 64][c8]) = ab1;
        }
        // ---- stage B ----
#pragma unroll
        for (int p = 0; p < 4; ++p)
            *(uint4*)(&Blds[p * 64 + rb][c8]) = *(const uint4*)(Wt + (long)(p * 64 + rb) * 256 + k0 + c8);

        __syncthreads();

        // prefetch next k-tile of A while MFMA runs
        if (kt < 3) {
            if constexpr (!A_BF16) {
#pragma unroll
                for (int p = 0; p < 4; ++p)
                    a4[p] = *(const float4*)((const float*)Aptr + srcA[p] * 256 + k0 + 64 + c4);
            } else {
                ab0 = *(const uint4*)(arow0 + k0 + 64);
                ab1 = *(const uint4*)(arow1 + k0 + 64);
            }
        }

#pragma unroll
        for (int ks = 0; ks < 2; ++ks) {
            const int kb = ks * 32 + (lane >> 4) * 8;
            bf16x8 a[4], b[4];
#pragma unroll
            for (int i = 0; i < 4; ++i)
                a[i] = *(const bf16x8*)(&Alds[wm * 64 + i * 16 + (lane & 15)][kb]);
#pragma unroll
            for (int j = 0; j < 4; ++j)
                b[j] = *(const bf16x8*)(&Blds[wn * 64 + j * 16 + (lane & 15)][kb]);
#pragma unroll
            for (int i = 0; i < 4; ++i)
#pragma unroll
                for (int j = 0; j < 4; ++j)
                    acc[i][j] = __builtin_amdgcn_mfma_f32_16x16x32_bf16(a[i], b[j], acc[i][j], 0, 0, 0);
        }

        __syncthreads();
    }

    // ---- epilogue ----
#pragma unroll
    for (int i = 0; i < 4; ++i) {
#pragma unroll
        for (int j = 0; j < 4; ++j) {
            const int col = wn * 64 + j * 16 + (lane & 15);
            const float bs = bias[col];
#pragma unroll
            for (int rj = 0; rj < 4; ++rj) {
                const int row = tm * 128 + wm * 64 + i * 16 + (lane >> 4) * 4 + rj;
                if (row < nrows) {
                    long drow = SCATTER ? (long)dstIdx[row] : (long)row;
                    float val = acc[i][j][rj] + bs;
                    if constexpr (OUT_F32)
                        ((float*)Out)[drow * ldo + col] = val;
                    else
                        ((unsigned short*)Out)[drow * ldo + col] = f2bf(val);
                }
            }
        }
    }
}

// ---------------------------------------------------------------------------
// Fused K|V GEMM: gather fp32 A rows ONCE, compute both K and V projections.
// Out[r][0:256] = A[src(r)] @ WtK^T + bK ; Out[r][256:512] = A[src(r)] @ WtV^T + bV
// Per k-tile: stage A + B_K, mfma->accK, stage B_V (same LDS), mfma->accV.
// ---------------------------------------------------------------------------
__global__ __launch_bounds__(512) void gemm_kv(
    const float* __restrict__ A,
    const int* __restrict__ srcIdx,
    const unsigned short* __restrict__ WtK,
    const unsigned short* __restrict__ WtV,
    const float* __restrict__ bK,
    const float* __restrict__ bV,
    unsigned short* __restrict__ Out,    // bf16 [nrows][512]
    int nrows) {
    __shared__ unsigned short Alds[128][72];
    __shared__ unsigned short Blds[256][72];

    const int tm = blockIdx.x;
    const int tid = threadIdx.x;
    const int wave = tid >> 6, lane = tid & 63;
    const int wm = wave >> 2, wn = wave & 3;

    const int c8 = (tid & 7) * 8;
    const int rb = tid >> 3;    // 0..63
    const int c4 = (tid & 15) * 4;
    const int ra = tid >> 4;    // 0..31

    f32x4 accK[4][4] = {};
    f32x4 accV[4][4] = {};

    long srcA[4];
#pragma unroll
    for (int p = 0; p < 4; ++p) {
        const int gr = tm * 128 + p * 32 + ra;
        srcA[p] = (gr < nrows) ? (long)srcIdx[gr] : 0;
    }
    float4 a4[4];
#pragma unroll
    for (int p = 0; p < 4; ++p)
        a4[p] = *(const float4*)(A + srcA[p] * 256 + c4);

    for (int kt = 0; kt < 4; ++kt) {
        const int k0 = kt * 64;

        // stage A (convert) + B_K
#pragma unroll
        for (int p = 0; p < 4; ++p) {
            unsigned int lo = (unsigned int)f2bf(a4[p].x) | ((unsigned int)f2bf(a4[p].y) << 16);
            unsigned int hi = (unsigned int)f2bf(a4[p].z) | ((unsigned int)f2bf(a4[p].w) << 16);
            *(uint2*)(&Alds[p * 32 + ra][c4]) = make_uint2(lo, hi);
        }
#pragma unroll
        for (int p = 0; p < 4; ++p)
            *(uint4*)(&Blds[p * 64 + rb][c8]) = *(const uint4*)(WtK + (long)(p * 64 + rb) * 256 + k0 + c8);

        __syncthreads();

        // prefetch next A k-tile during K-phase MFMA
        if (kt < 3) {
#pragma unroll
            for (int p = 0; p < 4; ++p)
                a4[p] = *(const float4*)(A + srcA[p] * 256 + k0 + 64 + c4);
        }

        // K phase
#pragma unroll
        for (int ks = 0; ks < 2; ++ks) {
            const int kb = ks * 32 + (lane >> 4) * 8;
            bf16x8 a[4], b[4];
#pragma unroll
            for (int i = 0; i < 4; ++i)
                a[i] = *(const bf16x8*)(&Alds[wm * 64 + i * 16 + (lane & 15)][kb]);
#pragma unroll
            for (int j = 0; j < 4; ++j)
                b[j] = *(const bf16x8*)(&Blds[wn * 64 + j * 16 + (lane & 15)][kb]);
#pragma unroll
            for (int i = 0; i < 4; ++i)
#pragma unroll
                for (int j = 0; j < 4; ++j)
                    accK[i][j] = __builtin_amdgcn_mfma_f32_16x16x32_bf16(a[i], b[j], accK[i][j], 0, 0, 0);
        }

        __syncthreads();

        // stage B_V over the same LDS
#pragma unroll
        for (int p = 0; p < 4; ++p)
            *(uint4*)(&Blds[p * 64 + rb][c8]) = *(const uint4*)(WtV + (long)(p * 64 + rb) * 256 + k0 + c8);

        __syncthreads();

        // V phase (A still staged)
#pragma unroll
        for (int ks = 0; ks < 2; ++ks) {
            const int kb = ks * 32 + (lane >> 4) * 8;
            bf16x8 a[4], b[4];
#pragma unroll
            for (int i = 0; i < 4; ++i)
                a[i] = *(const bf16x8*)(&Alds[wm * 64 + i * 16 + (lane & 15)][kb]);
#pragma unroll
            for (int j = 0; j < 4; ++j)
                b[j] = *(const bf16x8*)(&Blds[wn * 64 + j * 16 + (lane & 15)][kb]);
#pragma unroll
            for (int i = 0; i < 4; ++i)
#pragma unroll
                for (int j = 0; j < 4; ++j)
                    accV[i][j] = __builtin_amdgcn_mfma_f32_16x16x32_bf16(a[i], b[j], accV[i][j], 0, 0, 0);
        }

        __syncthreads();
    }

    // ---- epilogue: K cols [0,256), V cols [256,512) ----
#pragma unroll
    for (int i = 0; i < 4; ++i) {
#pragma unroll
        for (int j = 0; j < 4; ++j) {
            const int col = wn * 64 + j * 16 + (lane & 15);
            const float bk = bK[col];
            const float bv = bV[col];
#pragma unroll
            for (int rj = 0; rj < 4; ++rj) {
                const int row = tm * 128 + wm * 64 + i * 16 + (lane >> 4) * 4 + rj;
                if (row < nrows) {
                    Out[(long)row * 512 + col]       = f2bf(accK[i][j][rj] + bk);
                    Out[(long)row * 512 + 256 + col] = f2bf(accV[i][j][rj] + bv);
                }
            }
        }
    }
}

// ---------------------------------------------------------------------------
// CSR pooling: one wave per segment s; kv rows for s are [offsets[s],offsets[s+1]).
// score_h = <k[e,h,:], q[s,h,:]>*scale ; ew = exp(score) (shift-free; |score|<~1)
// pooled[s] = sum ew*v / sum ew, written bf16 IN PLACE over q[s].
// ---------------------------------------------------------------------------
__global__ __launch_bounds__(256) void pool_csr_kernel(
    unsigned short* __restrict__ q,          // bf16 [S][256] (in: q, out: pooled)
    const unsigned short* __restrict__ kv,   // bf16 [Msorted][512] (k | v)
    const int* __restrict__ offsets,         // [S+1]
    int S) {
    const int s = blockIdx.x * 4 + (threadIdx.x >> 6);
    if (s >= S) return;
    const int lane = threadIdx.x & 63;
    const int beg = offsets[s];
    const int end = offsets[s + 1];

    const ushort4 qv = *(const ushort4*)(q + (long)s * 256 + lane * 4);
    const float q0 = bf2f(qv.x), q1 = bf2f(qv.y), q2 = bf2f(qv.z), q3 = bf2f(qv.w);

    float a0 = 0.f, a1 = 0.f, a2 = 0.f, a3 = 0.f, denom = 0.f;

    for (int e = beg; e < end; ++e) {
        const ushort4 kk = *(const ushort4*)(kv + (long)e * 512 + lane * 4);
        const ushort4 vv = *(const ushort4*)(kv + (long)e * 512 + 256 + lane * 4);
        float p = q0 * bf2f(kk.x) + q1 * bf2f(kk.y) + q2 * bf2f(kk.z) + q3 * bf2f(kk.w);
        p += __shfl_xor(p, 1);
        p += __shfl_xor(p, 2);
        p += __shfl_xor(p, 4);   // 8-lane head group holds the head dot
        const float ew = expf(p * 0.17677669529663687f);  // 1/sqrt(32)
        a0 += ew * bf2f(vv.x);
        a1 += ew * bf2f(vv.y);
        a2 += ew * bf2f(vv.z);
        a3 += ew * bf2f(vv.w);
        denom += ew;
    }

    const float w = 1.0f / fmaxf(denom, 1e-9f);
    ushort4 o;
    o.x = f2bf(a0 * w);
    o.y = f2bf(a1 * w);
    o.z = f2bf(a2 * w);
    o.w = f2bf(a3 * w);
    *(ushort4*)(q + (long)s * 256 + lane * 4) = o;
}

// ---------------------------------------------------------------------------
extern "C" void kernel_launch(void* const* d_in, const int* in_sizes, int n_in,
                              void* d_out, int out_size, void* d_ws, size_t ws_size,
                              hipStream_t stream) {
    const float* enc  = (const float*)d_in[0];
    const float* W_q  = (const float*)d_in[1];
    const float* b_q  = (const float*)d_in[2];
    const float* W_k  = (const float*)d_in[3];
    const float* b_k  = (const float*)d_in[4];
    const float* W_v  = (const float*)d_in[5];
    const float* b_v  = (const float*)d_in[6];
    const float* W_o  = (const float*)d_in[7];
    const float* b_o  = (const float*)d_in[8];
    const int* map_key = (const int*)d_in[9];    // [M] ast idx
    const int* map_val = (const int*)d_in[10];   // [M] cfg idx (segment id)
    const int* pdg_key = (const int*)d_in[11];   // [S] dst rows (bijection)
    const int* pdg_val = (const int*)d_in[12];   // [S] src ast rows

    const int M = in_sizes[9];
    const int S = in_sizes[11];
    const int NB = (S + 255) / 256;

    char* ws = (char*)d_ws;
    size_t off = 0;
    auto alloc = [&](size_t bytes) -> char* {
        char* p = ws + off;
        off += (bytes + 255) & ~(size_t)255;
        return p;
    };

    unsigned short* Wt_q  = (unsigned short*)alloc(256 * 256 * 2);
    unsigned short* Wt_k  = (unsigned short*)alloc(256 * 256 * 2);
    unsigned short* Wt_v  = (unsigned short*)alloc(256 * 256 * 2);
    unsigned short* Wt_o  = (unsigned short*)alloc(256 * 256 * 2);
    int*            counts  = (int*)alloc((size_t)S * 4);
    int*            cursor  = (int*)alloc((size_t)S * 4);
    int*            offsets = (int*)alloc((size_t)(S + 1) * 4);
    int*            bsum    = (int*)alloc((size_t)NB * 4);
    int*            bpref   = (int*)alloc((size_t)NB * 4);
    int*            sorted_src = (int*)alloc((size_t)M * 4);
    unsigned short* qbuf  = (unsigned short*)alloc((size_t)S * 256 * 2);  // q, then pooled
    unsigned short* kvbuf = (unsigned short*)alloc((size_t)M * 512 * 2);

    // zero counts with a plain kernel (NOT hipMemsetAsync)
    zero_kernel<<<(S + 255) / 256, 256, 0, stream>>>(counts, S);

    convert_weights<<<1024, 256, 0, stream>>>(W_q, W_k, W_v, W_o, Wt_q, Wt_k, Wt_v, Wt_o);

    // counting sort of mapping entries by segment
    hist_kernel<<<(M + 255) / 256, 256, 0, stream>>>(map_val, counts, M);
    scan_p1<<<NB, 256, 0, stream>>>(counts, bsum, S);
    scan_p2<<<1, 256, 0, stream>>>(bsum, bpref, offsets, NB, S);
    scan_p3<<<NB, 256, 0, stream>>>(counts, bpref, offsets, cursor, S);
    scatter_kernel<<<(M + 255) / 256, 256, 0, stream>>>(
        map_key, map_val, cursor, sorted_src, M);

    // Q projection: q[pdg_key[i]] = enc[pdg_val[i]] @ W_q + b_q  (fp32 gather)
    gemm256<true, true, false, false><<<(S + 127) / 128, 512, 0, stream>>>(
        enc, pdg_val, pdg_key, Wt_q, b_q, qbuf, S, 256);

    // fused K|V projection: kv[i] = enc[sorted_src[i]] @ [W_k|W_v] + [b_k|b_v]
    gemm_kv<<<(M + 127) / 128, 512, 0, stream>>>(
        enc, sorted_src, Wt_k, Wt_v, b_k, b_v, kvbuf, M);

    // CSR segment softmax + pooling; pooled overwrites qbuf
    pool_csr_kernel<<<(S + 3) / 4, 256, 0, stream>>>(qbuf, kvbuf, offsets, S);

    // output projection to d_out (fp32)
    gemm256<false, false, true, true><<<(S + 127) / 128, 512, 0, stream>>>(
        qbuf, nullptr, nullptr, Wt_o, b_o, d_out, S, 256);
}